// Round 11
// baseline (1521.659 us; speedup 1.0000x reference)
//
#include <hip/hip_runtime.h>
#include <math.h>

#define B 2
#define S 1024
#define H 8
#define DIM 128
#define NCMP 63      // (1024-32)/16+1
#define NSLC 61      // (1024-64)/16+1
#define QB 64        // BLOCK_Q
#define NQB (S/QB)   // 16
#define WIN 128
#define SCALE  0.08838834764831845f   // 128^-0.5
#define RSCALE 11.313708498984761f    // 128^+0.5  (cmp branch divides by scale)

typedef float v2f __attribute__((ext_vector_type(2)));

// ---------------- kernel 1: compressed K/V ----------------
__global__ __launch_bounds__(64) void cmp_kv_kernel(
    const float* __restrict__ k, const float* __restrict__ v,
    const float* __restrict__ wck, const float* __restrict__ bck,
    const float* __restrict__ wcv, const float* __restrict__ bcv,
    float* __restrict__ Kc, float* __restrict__ Vc)
{
  const int d0 = threadIdx.x * 2;
  const int n = blockIdx.x, h = blockIdx.y, b = blockIdx.z;
  const size_t rs = (size_t)H * DIM;
  const float* kp = k + (size_t)b*S*rs + (size_t)(n*16)*rs + (size_t)h*DIM + d0;
  const float* vp = v + (kp - k);
  v2f sk = {0.f, 0.f}, sv = {0.f, 0.f};
  #pragma unroll
  for (int l = 0; l < 32; ++l) {
    v2f kk = *(const v2f*)(kp + (size_t)l*rs);
    v2f vv = *(const v2f*)(vp + (size_t)l*rs);
    sk += kk * wck[l];
    sv += vv * wcv[l];
  }
  sk += bck[0];
  sv += bcv[0];
  size_t oi = ((size_t)(b*H + h)*NCMP + n)*(size_t)DIM + d0;
  *(v2f*)(Kc + oi) = sk;
  *(v2f*)(Vc + oi) = sv;
}

// ---------------- wave reductions ----------------
__device__ __forceinline__ float wave_max(float x) {
  #pragma unroll
  for (int off = 32; off > 0; off >>= 1) x = fmaxf(x, __shfl_xor(x, off));
  return x;
}
__device__ __forceinline__ float wave_sum(float x) {
  #pragma unroll
  for (int off = 32; off > 0; off >>= 1) x += __shfl_xor(x, off);
  return x;
}
__device__ __forceinline__ int clampS(int r) { return r < 0 ? 0 : (r > S-1 ? S-1 : r); }
__device__ __forceinline__ float sigm(float x) { return 1.f / (1.f + __expf(-x)); }

// QK single tile: lane owns key; 4 queries broadcast; 4 v2f accumulators.
__device__ __forceinline__ float4 qk4(const float (*q_lds)[DIM], const float4 (*k4)[32],
                                      int q0, int lane) {
  v2f a0={0,0}, a1={0,0}, a2={0,0}, a3={0,0};
  const int jsw = lane & 7;
  #pragma unroll
  for (int g = 0; g < 32; ++g) {
    float4 kk = k4[lane][g ^ jsw];
    v2f k01 = {kk.x, kk.y}, k23 = {kk.z, kk.w};
    float4 qa = *(const float4*)&q_lds[q0+0][g<<2];
    float4 qb = *(const float4*)&q_lds[q0+1][g<<2];
    float4 qc = *(const float4*)&q_lds[q0+2][g<<2];
    float4 qd = *(const float4*)&q_lds[q0+3][g<<2];
    a0 += (v2f){qa.x,qa.y}*k01 + (v2f){qa.z,qa.w}*k23;
    a1 += (v2f){qb.x,qb.y}*k01 + (v2f){qb.z,qb.w}*k23;
    a2 += (v2f){qc.x,qc.y}*k01 + (v2f){qc.z,qc.w}*k23;
    a3 += (v2f){qd.x,qd.y}*k01 + (v2f){qd.z,qd.w}*k23;
  }
  float4 r;
  r.x = a0.x+a0.y; r.y = a1.x+a1.y; r.z = a2.x+a2.y; r.w = a3.x+a3.y;
  return r;
}

// QK paired tiles: one q-broadcast feeds two k-buffers (40% fewer LDS reads).
__device__ __forceinline__ void qk8(const float (*q_lds)[DIM],
                                    const float4 (*kA)[32], const float4 (*kB)[32],
                                    int q0, int lane, float4& rA, float4& rB) {
  v2f a0={0,0}, a1={0,0}, a2={0,0}, a3={0,0};
  v2f b0={0,0}, b1={0,0}, b2={0,0}, b3={0,0};
  const int jsw = lane & 7;
  #pragma unroll
  for (int g = 0; g < 32; ++g) {
    float4 ka = kA[lane][g ^ jsw];
    float4 kb_ = kB[lane][g ^ jsw];
    v2f ka01 = {ka.x, ka.y}, ka23 = {ka.z, ka.w};
    v2f kb01 = {kb_.x, kb_.y}, kb23 = {kb_.z, kb_.w};
    float4 qa = *(const float4*)&q_lds[q0+0][g<<2];
    float4 qb = *(const float4*)&q_lds[q0+1][g<<2];
    float4 qc = *(const float4*)&q_lds[q0+2][g<<2];
    float4 qd = *(const float4*)&q_lds[q0+3][g<<2];
    v2f qa01={qa.x,qa.y}, qa23={qa.z,qa.w};
    v2f qb01={qb.x,qb.y}, qb23={qb.z,qb.w};
    v2f qc01={qc.x,qc.y}, qc23={qc.z,qc.w};
    v2f qd01={qd.x,qd.y}, qd23={qd.z,qd.w};
    a0 += qa01*ka01 + qa23*ka23;  b0 += qa01*kb01 + qa23*kb23;
    a1 += qb01*ka01 + qb23*ka23;  b1 += qb01*kb01 + qb23*kb23;
    a2 += qc01*ka01 + qc23*ka23;  b2 += qc01*kb01 + qc23*kb23;
    a3 += qd01*ka01 + qd23*ka23;  b3 += qd01*kb01 + qd23*kb23;
  }
  rA.x = a0.x+a0.y; rA.y = a1.x+a1.y; rA.z = a2.x+a2.y; rA.w = a3.x+a3.y;
  rB.x = b0.x+b0.y; rB.y = b1.x+b1.y; rB.z = b2.x+b2.y; rB.w = b3.x+b3.y;
}

// PV: lane owns d-pair; p broadcast; v from LDS. Named accumulators.
__device__ __forceinline__ void pv_lds(const float (*v_lds)[DIM],
                                       const float (*p_lds)[64], int g0, int lane,
                                       v2f& c0, v2f& c1, v2f& c2, v2f& c3) {
  const int d0 = lane * 2;
  #pragma unroll 8
  for (int j = 0; j < 64; ++j) {
    float4 pv = *(const float4*)&p_lds[j][((g0 ^ (j & 15)) << 2)];
    v2f vv = *(const v2f*)&v_lds[j][d0];
    c0 += vv * pv.x;
    c1 += vv * pv.y;
    c2 += vv * pv.z;
    c3 += vv * pv.w;
  }
}

// ---------------- kernel W: window branch ----------------
__global__ __launch_bounds__(1024) void nsa_win(
    const float* __restrict__ qg, const float* __restrict__ kg, const float* __restrict__ vg,
    const float* __restrict__ wgate, const float* __restrict__ bgate,
    float* __restrict__ outg)
{
  __shared__ __align__(16) float q_lds[QB][DIM];   // 32 KB
  __shared__ float4 kb[2][64][32];                 // 64 KB
  __shared__ __align__(16) float v_lds[64][DIM];   // 32 KB
  __shared__ __align__(16) float p_lds[64][64];    // 16 KB
  __shared__ __align__(16) float gw[3][DIM];       // 1.5 KB  (~146 KB total)

  const int tid  = threadIdx.x;
  const int lane = tid & 63;
  const int wid  = tid >> 6;
  const int qb = blockIdx.x, h = blockIdx.y, b = blockIdx.z;
  const int q0  = wid * 4;
  const int iq0 = qb*QB + q0;
  const size_t rs = (size_t)H * DIM;
  const float* qg_bh = qg + (size_t)b*S*rs + (size_t)h*DIM;
  const float* kg_bh = kg + (size_t)b*S*rs + (size_t)h*DIM;
  const float* vg_bh = vg + (size_t)b*S*rs + (size_t)h*DIM;

  const int ju0  = tid >> 5;
  const int gu   = tid & 31;
  const int jsw0 = ju0 & 7;
  const int w0   = qb*QB - WIN;

  {
    int qrow = qb*QB + ju0;
    *(float4*)&q_lds[ju0][gu*4]    = *(const float4*)(qg_bh + (size_t)qrow*rs + gu*4);
    *(float4*)&q_lds[ju0+32][gu*4] = *(const float4*)(qg_bh + (size_t)(qrow+32)*rs + gu*4);
    if (tid < 384) gw[tid >> 7][tid & 127] = wgate[tid];
    kb[0][ju0][gu ^ jsw0]    = *(const float4*)(kg_bh + (size_t)clampS(w0+ju0)*rs + gu*4);
    kb[0][ju0+32][gu ^ jsw0] = *(const float4*)(kg_bh + (size_t)clampS(w0+ju0+32)*rs + gu*4);
    kb[1][ju0][gu ^ jsw0]    = *(const float4*)(kg_bh + (size_t)clampS(w0+64+ju0)*rs + gu*4);
    kb[1][ju0+32][gu ^ jsw0] = *(const float4*)(kg_bh + (size_t)clampS(w0+64+ju0+32)*rs + gu*4);
    *(float4*)&v_lds[ju0][gu*4]    = *(const float4*)(vg_bh + (size_t)clampS(w0+ju0)*rs + gu*4);
    *(float4*)&v_lds[ju0+32][gu*4] = *(const float4*)(vg_bh + (size_t)clampS(w0+ju0+32)*rs + gu*4);
  }
  __syncthreads();

  const int pcolg = ((wid ^ (lane & 15)) << 2);
  v2f c0={0,0}, c1={0,0}, c2={0,0}, c3={0,0};
  float4 lsum = {0.f,0.f,0.f,0.f};

  #pragma unroll 1
  for (int p = 0; p < 3; ++p) {
    const int rA = w0 + p*128;          // tile 2p
    const int rB = rA + 64;             // tile 2p+1
    float4 sA, sB;
    qk8(q_lds, kb[0], kb[1], q0, lane, sA, sB);

    // tile A softmax terms
    {
      int ja = rA + lane;
      bool jin = (ja >= 0) & (ja < S);
      float4 p4;
      { bool ok = jin & (ja >= iq0+0-WIN) & (ja <= iq0+0+WIN); p4.x = ok ? __expf(sA.x*SCALE) : 0.f; }
      { bool ok = jin & (ja >= iq0+1-WIN) & (ja <= iq0+1+WIN); p4.y = ok ? __expf(sA.y*SCALE) : 0.f; }
      { bool ok = jin & (ja >= iq0+2-WIN) & (ja <= iq0+2+WIN); p4.z = ok ? __expf(sA.z*SCALE) : 0.f; }
      { bool ok = jin & (ja >= iq0+3-WIN) & (ja <= iq0+3+WIN); p4.w = ok ? __expf(sA.w*SCALE) : 0.f; }
      lsum.x += p4.x; lsum.y += p4.y; lsum.z += p4.z; lsum.w += p4.w;
      *(float4*)&p_lds[lane][pcolg] = p4;
    }
    pv_lds(v_lds, p_lds, wid, lane, c0, c1, c2, c3);     // uses V(tile A)
    __syncthreads();
    // restage: v <- V(tile B); prefetch next k pair
    *(float4*)&v_lds[ju0][gu*4]    = *(const float4*)(vg_bh + (size_t)clampS(rB+ju0)*rs + gu*4);
    *(float4*)&v_lds[ju0+32][gu*4] = *(const float4*)(vg_bh + (size_t)clampS(rB+ju0+32)*rs + gu*4);
    if (p < 2) {
      kb[0][ju0][gu ^ jsw0]    = *(const float4*)(kg_bh + (size_t)clampS(rA+128+ju0)*rs + gu*4);
      kb[0][ju0+32][gu ^ jsw0] = *(const float4*)(kg_bh + (size_t)clampS(rA+128+ju0+32)*rs + gu*4);
      kb[1][ju0][gu ^ jsw0]    = *(const float4*)(kg_bh + (size_t)clampS(rA+192+ju0)*rs + gu*4);
      kb[1][ju0+32][gu ^ jsw0] = *(const float4*)(kg_bh + (size_t)clampS(rA+192+ju0+32)*rs + gu*4);
    }
    __syncthreads();

    // tile B softmax terms
    {
      int jb = rB + lane;
      bool jin = (jb >= 0) & (jb < S);
      float4 p4;
      { bool ok = jin & (jb >= iq0+0-WIN) & (jb <= iq0+0+WIN); p4.x = ok ? __expf(sB.x*SCALE) : 0.f; }
      { bool ok = jin & (jb >= iq0+1-WIN) & (jb <= iq0+1+WIN); p4.y = ok ? __expf(sB.y*SCALE) : 0.f; }
      { bool ok = jin & (jb >= iq0+2-WIN) & (jb <= iq0+2+WIN); p4.z = ok ? __expf(sB.z*SCALE) : 0.f; }
      { bool ok = jin & (jb >= iq0+3-WIN) & (jb <= iq0+3+WIN); p4.w = ok ? __expf(sB.w*SCALE) : 0.f; }
      lsum.x += p4.x; lsum.y += p4.y; lsum.z += p4.z; lsum.w += p4.w;
      *(float4*)&p_lds[lane][pcolg] = p4;
    }
    pv_lds(v_lds, p_lds, wid, lane, c0, c1, c2, c3);     // uses V(tile B)
    if (p < 2) {
      __syncthreads();
      *(float4*)&v_lds[ju0][gu*4]    = *(const float4*)(vg_bh + (size_t)clampS(rA+128+ju0)*rs + gu*4);
      *(float4*)&v_lds[ju0+32][gu*4] = *(const float4*)(vg_bh + (size_t)clampS(rA+128+ju0+32)*rs + gu*4);
      __syncthreads();
    }
  }

  const float bg2 = bgate[2];
  const int d0 = lane * 2;
  float lw0 = wave_sum(lsum.x), lw1 = wave_sum(lsum.y);
  float lw2 = wave_sum(lsum.z), lw3 = wave_sum(lsum.w);
  #pragma unroll
  for (int qq = 0; qq < 4; ++qq) {
    v2f qv = *(const v2f*)&q_lds[q0+qq][d0];
    v2f gwv = *(const v2f*)&gw[2][d0];
    float g2 = sigm(wave_sum(qv.x*gwv.x + qv.y*gwv.y) + bg2);
    float lw = (qq==0)?lw0:(qq==1)?lw1:(qq==2)?lw2:lw3;
    v2f acc = (qq==0)?c0:(qq==1)?c1:(qq==2)?c2:c3;
    v2f o = acc * (g2 / lw);
    size_t oi = (size_t)b*S*rs + (size_t)(iq0+qq)*rs + (size_t)h*DIM + d0;
    *(v2f*)(outg + oi) = o;
  }
}

// ---------------- kernel C: cmp + selection + slc, combine into out ----------------
__global__ __launch_bounds__(1024) void nsa_cs(
    const float* __restrict__ qg, const float* __restrict__ kg, const float* __restrict__ vg,
    const float* __restrict__ Kc, const float* __restrict__ Vc,
    const float* __restrict__ wgate, const float* __restrict__ bgate,
    float* outg)
{
  __shared__ __align__(16) float q_lds[QB][DIM];
  __shared__ float4 kb[2][64][32];
  __shared__ __align__(16) float v_lds[64][DIM];
  __shared__ __align__(16) float p_lds[64][64];
  __shared__ __align__(16) float gw[3][DIM];
  __shared__ float S_col[64];
  __shared__ int sel[2];

  const int tid  = threadIdx.x;
  const int lane = tid & 63;
  const int wid  = tid >> 6;
  const int qb = blockIdx.x, h = blockIdx.y, b = blockIdx.z;
  const int bh = b*H + h;
  const int q0  = wid * 4;
  const int iq0 = qb*QB + q0;
  const size_t rs = (size_t)H * DIM;
  const float* qg_bh = qg + (size_t)b*S*rs + (size_t)h*DIM;
  const float* kg_bh = kg + (size_t)b*S*rs + (size_t)h*DIM;
  const float* vg_bh = vg + (size_t)b*S*rs + (size_t)h*DIM;
  const float* KcBH  = Kc + (size_t)bh*NCMP*DIM;
  const float* VcBH  = Vc + (size_t)bh*NCMP*DIM;

  const int ju0  = tid >> 5;
  const int gu   = tid & 31;
  const int jsw0 = ju0 & 7;

  {
    int qrow = qb*QB + ju0;
    *(float4*)&q_lds[ju0][gu*4]    = *(const float4*)(qg_bh + (size_t)qrow*rs + gu*4);
    *(float4*)&q_lds[ju0+32][gu*4] = *(const float4*)(qg_bh + (size_t)(qrow+32)*rs + gu*4);
    if (tid < 384) gw[tid >> 7][tid & 127] = wgate[tid];
    int rc1 = (ju0+32 < NCMP) ? ju0+32 : NCMP-1;       // row 63 dup (masked)
    kb[0][ju0][gu ^ jsw0]    = *(const float4*)(KcBH + (size_t)ju0*DIM + gu*4);
    kb[0][ju0+32][gu ^ jsw0] = *(const float4*)(KcBH + (size_t)rc1*DIM + gu*4);
    *(float4*)&v_lds[ju0][gu*4]    = *(const float4*)(VcBH + (size_t)ju0*DIM + gu*4);
    *(float4*)&v_lds[ju0+32][gu*4] = *(const float4*)(VcBH + (size_t)rc1*DIM + gu*4);
  }
  __syncthreads();   // b0

  const int pcolg = ((wid ^ (lane & 15)) << 2);

  // cmp: fp32, max-subtracted (logits std ~128), normalized p (needed for top-k)
  v2f cc0={0,0}, cc1={0,0}, cc2={0,0}, cc3={0,0};
  {
    float4 sc = qk4(q_lds, kb[0], q0, lane);
    float4 p4;
    { float s = (lane<NCMP)? sc.x*RSCALE : -INFINITY; float m=wave_max(s);
      float p=__expf(s-m); p4.x = p*(1.f/wave_sum(p)); }
    { float s = (lane<NCMP)? sc.y*RSCALE : -INFINITY; float m=wave_max(s);
      float p=__expf(s-m); p4.y = p*(1.f/wave_sum(p)); }
    { float s = (lane<NCMP)? sc.z*RSCALE : -INFINITY; float m=wave_max(s);
      float p=__expf(s-m); p4.z = p*(1.f/wave_sum(p)); }
    { float s = (lane<NCMP)? sc.w*RSCALE : -INFINITY; float m=wave_max(s);
      float p=__expf(s-m); p4.w = p*(1.f/wave_sum(p)); }
    *(float4*)&p_lds[lane][pcolg] = p4;
    pv_lds(v_lds, p_lds, wid, lane, cc0, cc1, cc2, cc3);
  }
  __syncthreads();   // b1

  if (wid == 0) {
    float ssum = 0.f;
    const int gx = lane & 15;
    #pragma unroll
    for (int g = 0; g < 16; ++g) {
      float4 t4 = *(const float4*)&p_lds[lane][(g ^ gx) << 2];
      ssum += (t4.x + t4.y) + (t4.z + t4.w);
    }
    S_col[lane] = ssum;
    asm volatile("s_waitcnt lgkmcnt(0)" ::: "memory");
    float val = -INFINITY;
    if (lane < NSLC) {
      const float wts[5] = {1.f, 2.f, 2.f, 2.f, 1.f};
      float a = 0.f;
      #pragma unroll
      for (int o = 0; o < 5; ++o) {
        int i = 4*lane - o;
        if (i >= 0 && i < NCMP) a += wts[o] * S_col[i];
      }
      val = a;
    }
    float v1 = val; int i1 = lane;
    #pragma unroll
    for (int off = 32; off > 0; off >>= 1) {
      float ov = __shfl_xor(v1, off); int oi = __shfl_xor(i1, off);
      if (ov > v1 || (ov == v1 && oi < i1)) { v1 = ov; i1 = oi; }
    }
    int s0i = i1;
    float v2 = (lane == s0i) ? -INFINITY : val; int i2 = lane;
    #pragma unroll
    for (int off = 32; off > 0; off >>= 1) {
      float ov = __shfl_xor(v2, off); int oi = __shfl_xor(i2, off);
      if (ov > v2 || (ov == v2 && oi < i2)) { v2 = ov; i2 = oi; }
    }
    if (lane == 0) { sel[0] = s0i; sel[1] = i2; }
  }
  __syncthreads();   // b2

  const int rowA = sel[0] * 16;     // rows always within [0, 1023]
  const int rowB = sel[1] * 16;
  {
    kb[0][ju0][gu ^ jsw0]    = *(const float4*)(kg_bh + (size_t)(rowA+ju0)*rs + gu*4);
    kb[0][ju0+32][gu ^ jsw0] = *(const float4*)(kg_bh + (size_t)(rowA+ju0+32)*rs + gu*4);
    kb[1][ju0][gu ^ jsw0]    = *(const float4*)(kg_bh + (size_t)(rowB+ju0)*rs + gu*4);
    kb[1][ju0+32][gu ^ jsw0] = *(const float4*)(kg_bh + (size_t)(rowB+ju0+32)*rs + gu*4);
    *(float4*)&v_lds[ju0][gu*4]    = *(const float4*)(vg_bh + (size_t)(rowA+ju0)*rs + gu*4);
    *(float4*)&v_lds[ju0+32][gu*4] = *(const float4*)(vg_bh + (size_t)(rowA+ju0+32)*rs + gu*4);
  }
  __syncthreads();   // b3

  // slc: paired QK, deferred-norm softmax (logits ~N(0,1))
  v2f cs0={0,0}, cs1={0,0}, cs2={0,0}, cs3={0,0};
  float4 sA, sB;
  qk8(q_lds, kb[0], kb[1], q0, lane, sA, sB);
  float4 pA, pB, lsumS;
  pA.x = __expf(sA.x*SCALE); pA.y = __expf(sA.y*SCALE);
  pA.z = __expf(sA.z*SCALE); pA.w = __expf(sA.w*SCALE);
  pB.x = __expf(sB.x*SCALE); pB.y = __expf(sB.y*SCALE);
  pB.z = __expf(sB.z*SCALE); pB.w = __expf(sB.w*SCALE);
  lsumS.x = pA.x+pB.x; lsumS.y = pA.y+pB.y; lsumS.z = pA.z+pB.z; lsumS.w = pA.w+pB.w;
  *(float4*)&p_lds[lane][pcolg] = pA;
  pv_lds(v_lds, p_lds, wid, lane, cs0, cs1, cs2, cs3);   // V[rowA]
  __syncthreads();   // b4
  *(float4*)&v_lds[ju0][gu*4]    = *(const float4*)(vg_bh + (size_t)(rowB+ju0)*rs + gu*4);
  *(float4*)&v_lds[ju0+32][gu*4] = *(const float4*)(vg_bh + (size_t)(rowB+ju0+32)*rs + gu*4);
  __syncthreads();   // b5
  *(float4*)&p_lds[lane][pcolg] = pB;
  pv_lds(v_lds, p_lds, wid, lane, cs0, cs1, cs2, cs3);   // V[rowB]

  // combine: out += g0*cmp + (g1/lS)*slc  (out already holds g2-weighted window)
  const float bg0 = bgate[0], bg1 = bgate[1];
  const int d0 = lane * 2;
  float ls0 = wave_sum(lsumS.x), ls1 = wave_sum(lsumS.y);
  float ls2 = wave_sum(lsumS.z), ls3 = wave_sum(lsumS.w);
  #pragma unroll
  for (int qq = 0; qq < 4; ++qq) {
    v2f qv = *(const v2f*)&q_lds[q0+qq][d0];
    v2f gw0v = *(const v2f*)&gw[0][d0];
    v2f gw1v = *(const v2f*)&gw[1][d0];
    float g0 = sigm(wave_sum(qv.x*gw0v.x + qv.y*gw0v.y) + bg0);
    float g1 = sigm(wave_sum(qv.x*gw1v.x + qv.y*gw1v.y) + bg1);
    float ls = (qq==0)?ls0:(qq==1)?ls1:(qq==2)?ls2:ls3;
    v2f ac = (qq==0)?cc0:(qq==1)?cc1:(qq==2)?cc2:cc3;
    v2f as = (qq==0)?cs0:(qq==1)?cs1:(qq==2)?cs2:cs3;
    size_t oi = (size_t)b*S*rs + (size_t)(iq0+qq)*rs + (size_t)h*DIM + d0;
    v2f o = *(v2f*)(outg + oi);
    o += ac*g0 + as*(g1/ls);
    *(v2f*)(outg + oi) = o;
  }
}

extern "C" void kernel_launch(void* const* d_in, const int* in_sizes, int n_in,
                              void* d_out, int out_size, void* d_ws, size_t ws_size,
                              hipStream_t stream) {
  const float* q   = (const float*)d_in[0];
  const float* k   = (const float*)d_in[1];
  const float* v   = (const float*)d_in[2];
  const float* wck = (const float*)d_in[3];
  const float* bck = (const float*)d_in[4];
  const float* wcv = (const float*)d_in[5];
  const float* bcv = (const float*)d_in[6];
  const float* wg  = (const float*)d_in[7];
  const float* bg  = (const float*)d_in[8];
  float* out = (float*)d_out;

  float* Kc = (float*)d_ws;
  float* Vc = Kc + (size_t)B*H*NCMP*DIM;

  cmp_kv_kernel<<<dim3(NCMP, H, B), 64, 0, stream>>>(k, v, wck, bck, wcv, bcv, Kc, Vc);
  nsa_win<<<dim3(NQB, H, B), 1024, 0, stream>>>(q, k, v, wg, bg, out);
  nsa_cs<<<dim3(NQB, H, B), 1024, 0, stream>>>(q, k, v, Kc, Vc, wg, bg, out);
}